// Round 9
// baseline (1766.187 us; speedup 1.0000x reference)
//
#include <hip/hip_runtime.h>
#include <stdint.h>

// DecoderRNN: B=256, NSTEPS=128, I=128, H=1024, V=1024, teacher-forced GRU.
// Round 9: wave-autonomous persistent kernel. No intra-step barriers; h read
// direct global->register (sc0|sc1) with depth-3 pipeline; per-wave flag sync
// (flags[rB*4+wv][c]); every in-loop VMEM op is inline asm (exact vmcnt
// ledger); E/tok prefetched one step ahead; fast exp2/rcp gates.
//   LDS (96KB): [0,64K) W12 z,n gates; [64K,96K) Wout (startup temp: gate-r).
//   W_hh gate-r slice in registers (32 bf16x8).

#define NSTEP 128

typedef unsigned short u16;
typedef unsigned int u32;
typedef __attribute__((ext_vector_type(8))) short bf16x8;
typedef __attribute__((ext_vector_type(4))) int i32x4;
typedef __attribute__((ext_vector_type(4))) float f32x4;

typedef __attribute__((address_space(3))) void lds_void;
typedef const __attribute__((address_space(1))) void glb_void;
#define GLD16(g, l) __builtin_amdgcn_global_load_lds((glb_void*)(g), (lds_void*)(l), 16, 0, 0)

#if __has_builtin(__builtin_amdgcn_exp2f)
#define EXP2(x) __builtin_amdgcn_exp2f(x)
#else
#define EXP2(x) exp2f(x)
#endif
#if __has_builtin(__builtin_amdgcn_rcpf)
#define RCP(x) __builtin_amdgcn_rcpf(x)
#else
#define RCP(x) (1.0f / (x))
#endif

__device__ __forceinline__ u16 f2bf(float f) {
    u32 u = __float_as_uint(f);
    u = (u + 0x7FFFu + ((u >> 16) & 1u)) >> 16;
    return (u16)u;
}
__device__ __forceinline__ float fsigmoid(float x) {
    return RCP(1.f + EXP2(x * -1.44269504f));
}
__device__ __forceinline__ float ftanh(float x) {
    x = fminf(fmaxf(x, -18.f), 18.f);
    float t = EXP2(x * 2.88539008f);
    return (t - 1.f) * RCP(t + 1.f);
}

// ---- exact-count asm memory ops --------------------------------------------
__device__ __forceinline__ void gload4c(bf16x8& d0, bf16x8& d1, bf16x8& d2, bf16x8& d3,
                                        const u16* a) { // 4 vmcnt events, coherent
    asm volatile(
        "global_load_dwordx4 %0, %4, off sc0 sc1\n\t"
        "global_load_dwordx4 %1, %4, off offset:64 sc0 sc1\n\t"
        "global_load_dwordx4 %2, %4, off offset:128 sc0 sc1\n\t"
        "global_load_dwordx4 %3, %4, off offset:192 sc0 sc1"
        : "=&v"(d0), "=&v"(d1), "=&v"(d2), "=&v"(d3) : "v"(a) : "memory");
}
__device__ __forceinline__ void gloadf(float& d, const float* a) { // 1 event
    asm volatile("global_load_dword %0, %1, off" : "=&v"(d) : "v"(a) : "memory");
}
__device__ __forceinline__ void gloadi4(i32x4& d, const int* a) { // 1 event
    asm volatile("global_load_dwordx4 %0, %1, off" : "=&v"(d) : "v"(a) : "memory");
}
__device__ __forceinline__ void gstore_short_c(u16* a, u32 v) { // 1 event, coherent
    asm volatile("global_store_short %0, %1, off sc0 sc1" ::"v"(a), "v"(v) : "memory");
}
__device__ __forceinline__ void gstoref(float* a, float v) { // 1 event
    asm volatile("global_store_dword %0, %1, off" ::"v"(a), "v"(v) : "memory");
}

// ---- elementwise fp32 -> bf16 cast (1024 columns per row) ------------------
__global__ void cast_k(const float* __restrict__ src, int ld, int off, int relu,
                       u16* __restrict__ dst, int n) {
    for (int i = blockIdx.x * blockDim.x + threadIdx.x; i < n; i += gridDim.x * blockDim.x) {
        int row = i >> 10, col = i & 1023;
        float v = src[(long)row * ld + off + col];
        if (relu) v = fmaxf(v, 0.f);
        dst[i] = f2bf(v);
    }
}

// ---- small fp32 GEMM: C[b][n] = z[b]·W[n, off:off+128] + bias[n] (+bias2) --
__global__ void smallgemm_k(const float* __restrict__ z, const float* __restrict__ W,
                            int ldw, int off, const float* __restrict__ bias,
                            const float* __restrict__ bias2, int n2max,
                            float* __restrict__ C, u16* __restrict__ Cbf, int N) {
    int n = blockIdx.x;
    int b = threadIdx.x;
    float acc = bias[n] + ((bias2 && n < n2max) ? bias2[n] : 0.f);
    const float* zr = z + b * 128;
    const float* wr = W + (long)n * ldw + off;
#pragma unroll 8
    for (int k = 0; k < 128; ++k) acc += zr[k] * wr[k];
    C[b * N + n] = acc;
    if (Cbf) Cbf[b * N + n] = f2bf(acc);
}

// ---- E table GEMM: E[v][n] = relu(embed)[v]·Wihh[n]  (M=1024,N=3072,K=1024)
__global__ __launch_bounds__(256) void egemm_k(const u16* __restrict__ A,
                                               const u16* __restrict__ W,
                                               float* __restrict__ C) {
    __shared__ __align__(16) u16 lds[2][160 * 64];
    int tid = threadIdx.x, lane = tid & 63, wv = tid >> 6;
    int r0 = (blockIdx.x & 31) * 32;
    int n0 = (blockIdx.x >> 5) * 128;

    f32x4 acc[2][2];
#pragma unroll
    for (int m = 0; m < 2; ++m)
#pragma unroll
        for (int n = 0; n < 2; ++n) acc[m][n] = (f32x4){0.f, 0.f, 0.f, 0.f};

    auto stage = [&](int k0, int bufi) {
#pragma unroll
        for (int r = 0; r < 5; ++r) {
            int L = r * 256 + tid;
            int row = L >> 3;
            int c4 = (L & 7) ^ (row & 7);
            const u16* src = (row < 32)
                                 ? A + (long)(r0 + row) * 1024 + k0 + c4 * 8
                                 : W + (long)(n0 + row - 32) * 1024 + k0 + c4 * 8;
            GLD16(src, &lds[bufi][L * 8]);
        }
    };
    stage(0, 0);
    stage(64, 1);
    for (int it = 0; it < 16; ++it) {
        if (it < 15) asm volatile("s_waitcnt vmcnt(5)" ::: "memory");
        else         asm volatile("s_waitcnt vmcnt(0)" ::: "memory");
        __builtin_amdgcn_s_barrier();
        const char* base = (const char*)&lds[it & 1][0];
        bf16x8 af[2][2], bfr[2][2];
#pragma unroll
        for (int ks = 0; ks < 2; ++ks)
#pragma unroll
            for (int q = 0; q < 2; ++q) {
                int kb = ks * 64 + ((lane >> 4) << 4);
                int rowa = q * 16 + (lane & 15);
                af[ks][q] = *(const bf16x8*)(base + rowa * 128 + (kb ^ ((rowa & 7) << 4)));
                int rowb = 32 + wv * 32 + q * 16 + (lane & 15);
                bfr[ks][q] = *(const bf16x8*)(base + rowb * 128 + (kb ^ ((rowb & 7) << 4)));
            }
#pragma unroll
        for (int ks = 0; ks < 2; ++ks)
#pragma unroll
            for (int m = 0; m < 2; ++m)
#pragma unroll
                for (int n = 0; n < 2; ++n)
                    acc[m][n] = __builtin_amdgcn_mfma_f32_16x16x32_bf16(af[ks][m], bfr[ks][n],
                                                                        acc[m][n], 0, 0, 0);
        asm volatile("s_waitcnt lgkmcnt(0)" ::: "memory");
        __builtin_amdgcn_s_barrier();
        if (it + 2 < 16) stage((it + 2) * 64, it & 1);
    }
#pragma unroll
    for (int m = 0; m < 2; ++m)
#pragma unroll
        for (int n = 0; n < 2; ++n)
#pragma unroll
            for (int r = 0; r < 4; ++r) {
                int row = r0 + m * 16 + ((lane >> 4) << 2) + r;
                int col = n0 + wv * 32 + n * 16 + (lane & 15);
                C[(long)row * 3072 + col] = acc[m][n][r];
            }
}

// ---- persistent decoder (wave-autonomous) -----------------------------------
__global__ __launch_bounds__(256, 1) void decoder_k(
    const u16* __restrict__ Whh,    // [3072][1024] bf16
    const u16* __restrict__ Wout,   // [1024][1024] bf16
    const float* __restrict__ E,    // [1024][3072]
    const float* __restrict__ Zih2, // [256][3072]  (b_ih folded; +b_hh for r,z)
    const float* __restrict__ Zout, // [256][1024]  (out_b folded)
    const float* __restrict__ bhh,  // [3072]
    const int* __restrict__ toks,   // [128][256]
    const float* __restrict__ h0f,  // [256][1024] fp32
    u16* __restrict__ Hx,           // [2][256][1024] bf16 ping-pong
    float* __restrict__ out,        // [256][128][1024]
    u32* __restrict__ flags) {      // [16][64] per-(rB,wv,c) step flags
    __shared__ __align__(16) char L[98304];
    const int tid = threadIdx.x, lane = tid & 63, wv = tid >> 6;
    const int bid = blockIdx.x;
    const int rB = bid >> 6; // rows rB*64..+63
    const int c = bid & 63;  // cols c*16..+15

    // ---- startup: gate-r -> temp(Wout region) -> regs; then W12 + Wout ----
#pragma unroll
    for (int r = 0; r < 8; ++r) {
        int l = r * 256 + tid, row = l >> 7, ck = (l & 127) ^ (row & 15);
        GLD16(Whh + (long)(c * 16 + row) * 1024 + ck * 8, &L[65536 + l * 16]);
    }
    asm volatile("s_waitcnt vmcnt(0)" ::: "memory");
    __syncthreads();
    bf16x8 w0[32]; // gate-r B-fragments [it*4+ks], persistent in VGPRs
#pragma unroll
    for (int it = 0; it < 8; ++it)
#pragma unroll
        for (int ks = 0; ks < 4; ++ks) {
            int row = lane & 15, kc = it * 16 + ks * 4 + (lane >> 4);
            w0[it * 4 + ks] = *(const bf16x8*)(L + 65536 + row * 2048 + ((kc ^ row) << 4));
        }
    asm volatile("s_waitcnt lgkmcnt(0)" ::: "memory");
    __syncthreads();
#pragma unroll
    for (int r = 0; r < 16; ++r) {
        int l = r * 256 + tid, row = l >> 7, ck = (l & 127) ^ (row & 15);
        GLD16(Whh + (long)((1 + (row >> 4)) * 1024 + c * 16 + (row & 15)) * 1024 + ck * 8,
              &L[l * 16]);
    }
#pragma unroll
    for (int r = 0; r < 8; ++r) {
        int l = r * 256 + tid, row = l >> 7, ck = (l & 127) ^ (row & 15);
        GLD16(Wout + (long)(c * 16 + row) * 1024 + ck * 8, &L[65536 + l * 16]);
    }
    asm volatile("s_waitcnt vmcnt(0)" ::: "memory");
    __syncthreads(); // weights in LDS are read-only from here; no more barriers

    // ---- per-thread step-invariant state (all pre-ledger C loads) ----
    const int bbase = rB * 64 + wv * 16 + ((lane >> 4) << 2); // rows bbase..+3
    const int j = c * 16 + (lane & 15);
    const int hoff = (rB * 64 + wv * 16 + (lane & 15)) * 1024 + ((lane >> 4) << 3);
    const float bhn = bhh[2048 + j];
    float hprev[4], zi0[4], zi1[4], zi2[4], zo[4];
#pragma unroll
    for (int r = 0; r < 4; ++r) {
        int b = bbase + r;
        hprev[r] = h0f[b * 1024 + j];
        zi0[r] = Zih2[(long)b * 3072 + j];
        zi1[r] = Zih2[(long)b * 3072 + 1024 + j];
        zi2[r] = Zih2[(long)b * 3072 + 2048 + j];
        zo[r] = Zout[b * 1024 + j];
    }
    const int grp = rB * 4 + wv;
    u32* gflag = flags + grp * 64 + c;
    const u32* gf = flags + grp * 64;

    // prologue: E_cur for s=0 (tok = SOS = 0)
    float ec0[4], ec1[4], ec2[4];
#pragma unroll
    for (int r = 0; r < 4; ++r) {
        const float* eb = E + j;
        gloadf(ec0[r], eb);
        gloadf(ec1[r], eb + 1024);
        gloadf(ec2[r], eb + 2048);
    }

    for (int s = 0; s <= NSTEP; ++s) {
        // top: tok for step s+1 (oldest in ledger -> free)
        i32x4 tokv;
        if (s < NSTEP) gloadi4(tokv, toks + s * 256 + bbase);
        const u16* hL = Hx + (size_t)(s & 1) * 262144 + hoff;
        bf16x8 afq[8][4];
        gload4c(afq[0][0], afq[0][1], afq[0][2], afq[0][3], hL);
        gload4c(afq[1][0], afq[1][1], afq[1][2], afq[1][3], hL + 128);
        gload4c(afq[2][0], afq[2][1], afq[2][2], afq[2][3], hL + 256);

        f32x4 a0 = {0.f, 0.f, 0.f, 0.f}, a1 = a0, a2 = a0, aO = a0;
#pragma unroll
        for (int it = 0; it < 8; ++it) {
            if (it < 5)
                gload4c(afq[it + 3][0], afq[it + 3][1], afq[it + 3][2], afq[it + 3][3],
                        hL + (it + 3) * 128);
            // ledger: retire L(it); newer = remaining prefetched L's only
            if (it < 5)      asm volatile("s_waitcnt vmcnt(12)" ::: "memory");
            else if (it == 5) asm volatile("s_waitcnt vmcnt(8)" ::: "memory");
            else if (it == 6) asm volatile("s_waitcnt vmcnt(4)" ::: "memory");
            else              asm volatile("s_waitcnt vmcnt(0)" ::: "memory");
            __builtin_amdgcn_sched_barrier(0); // rule 18: pin consumers below
#pragma unroll
            for (int ks = 0; ks < 4; ++ks) // gate r from registers
                a0 = __builtin_amdgcn_mfma_f32_16x16x32_bf16(afq[it][ks], w0[it * 4 + ks],
                                                             a0, 0, 0, 0);
#pragma unroll
            for (int ks = 0; ks < 4; ++ks) { // gate z from W12
                int row = lane & 15, kc = it * 16 + ks * 4 + (lane >> 4);
                bf16x8 wg = *(const bf16x8*)(L + row * 2048 + ((kc ^ row) << 4));
                a1 = __builtin_amdgcn_mfma_f32_16x16x32_bf16(afq[it][ks], wg, a1, 0, 0, 0);
            }
#pragma unroll
            for (int ks = 0; ks < 4; ++ks) { // gate n from W12
                int row = 16 + (lane & 15), kc = it * 16 + ks * 4 + (lane >> 4);
                bf16x8 wg = *(const bf16x8*)(L + row * 2048 + ((kc ^ (row & 15)) << 4));
                a2 = __builtin_amdgcn_mfma_f32_16x16x32_bf16(afq[it][ks], wg, a2, 0, 0, 0);
            }
#pragma unroll
            for (int ks = 0; ks < 4; ++ks) { // OUT from WoutL
                int row = lane & 15, kc = it * 16 + ks * 4 + (lane >> 4);
                bf16x8 wo = *(const bf16x8*)(L + 65536 + row * 2048 + ((kc ^ row) << 4));
                aO = __builtin_amdgcn_mfma_f32_16x16x32_bf16(afq[it][ks], wo, aO, 0, 0, 0);
            }
        }

        // epilogue ledger: [OUT(4), h(4), E_next(12)] -> vmcnt(12) retires h
        if (s >= 1) {
#pragma unroll
            for (int r = 0; r < 4; ++r)
                gstoref(out + (long)(bbase + r) * 131072 + (long)(s - 1) * 1024 + j,
                        aO[r] + zo[r]);
        }
        if (s < NSTEP) {
            u16* hdst = Hx + (size_t)((s + 1) & 1) * 262144;
#pragma unroll
            for (int r = 0; r < 4; ++r) {
                float rg = fsigmoid(ec0[r] + zi0[r] + a0[r]);
                float zg = fsigmoid(ec1[r] + zi1[r] + a1[r]);
                float nn = ftanh(ec2[r] + zi2[r] + rg * (a2[r] + bhn));
                float hv = (1.f - zg) * nn + zg * hprev[r];
                hprev[r] = hv;
                gstore_short_c(hdst + (bbase + r) * 1024 + j, (u32)f2bf(hv));
            }
            // E_next for s+1 (exactly 12 asm loads; retired by next step's waits)
            float en0[4], en1[4], en2[4];
#pragma unroll
            for (int r = 0; r < 4; ++r) {
                const float* eb = E + (long)tokv[r] * 3072 + j;
                gloadf(en0[r], eb);
                gloadf(en1[r], eb + 1024);
                gloadf(en2[r], eb + 2048);
            }
            asm volatile("s_waitcnt vmcnt(12)" ::: "memory"); // h stores committed
            __builtin_amdgcn_sched_barrier(0);
            if (lane == 0)
                __hip_atomic_store(gflag, (u32)(s + 1), __ATOMIC_RELAXED,
                                   __HIP_MEMORY_SCOPE_AGENT);
            const u32 tgt = (u32)(s + 1);
            while (true) {
                u32 v = __hip_atomic_load(gf + lane, __ATOMIC_RELAXED,
                                          __HIP_MEMORY_SCOPE_AGENT);
                if (__all(v >= tgt)) break;
                __builtin_amdgcn_s_sleep(1);
            }
            __builtin_amdgcn_sched_barrier(0); // E_next regs safe below (poll drained vm)
#pragma unroll
            for (int r = 0; r < 4; ++r) {
                ec0[r] = en0[r];
                ec1[r] = en1[r];
                ec2[r] = en2[r];
            }
        }
    }
}

extern "C" void kernel_launch(void* const* d_in, const int* in_sizes, int n_in,
                              void* d_out, int out_size, void* d_ws, size_t ws_size,
                              hipStream_t stream) {
    const float* z = (const float*)d_in[0];
    const int* toks = (const int*)d_in[1];
    const float* embed_w = (const float*)d_in[3];
    const float* z2h_w = (const float*)d_in[4];
    const float* z2h_b = (const float*)d_in[5];
    const float* w_ih = (const float*)d_in[6];
    const float* b_ih = (const float*)d_in[7];
    const float* w_hh = (const float*)d_in[8];
    const float* b_hh = (const float*)d_in[9];
    const float* out_w = (const float*)d_in[10];
    const float* out_b = (const float*)d_in[11];
    float* out = (float*)d_out;

    char* ws = (char*)d_ws;
    size_t off = 0;
    auto alloc = [&](size_t bytes) {
        char* p = ws + off;
        off += (bytes + 255) & ~(size_t)255;
        return p;
    };
    u16* Whh_bf = (u16*)alloc(3072ull * 1024 * 2);
    u16* Wout_bf = (u16*)alloc(1024ull * 1024 * 2);
    u16* Wihh_bf = (u16*)alloc(3072ull * 1024 * 2);
    u16* Emb_bf = (u16*)alloc(1024ull * 1024 * 2);
    float* E = (float*)alloc(1024ull * 3072 * 4);
    float* Zih = (float*)alloc(256ull * 3072 * 4);
    float* Zout = (float*)alloc(256ull * 1024 * 4);
    float* hf = (float*)alloc(256ull * 1024 * 4);
    u16* Hx = (u16*)alloc(2ull * 256 * 1024 * 2);
    u32* flags = (u32*)alloc(4096);
    // total ws use ~34.5 MB

    hipMemsetAsync(flags, 0, 4096, stream);
    cast_k<<<2048, 256, 0, stream>>>(w_hh, 1024, 0, 0, Whh_bf, 3072 * 1024);
    cast_k<<<2048, 256, 0, stream>>>(out_w, 1152, 0, 0, Wout_bf, 1024 * 1024);
    cast_k<<<2048, 256, 0, stream>>>(w_ih, 1152, 0, 0, Wihh_bf, 3072 * 1024);
    cast_k<<<1024, 256, 0, stream>>>(embed_w, 1024, 0, 1, Emb_bf, 1024 * 1024);
    smallgemm_k<<<1024, 256, 0, stream>>>(z, z2h_w, 128, 0, z2h_b, nullptr, 0, hf, Hx, 1024);
    smallgemm_k<<<3072, 256, 0, stream>>>(z, w_ih, 1152, 1024, b_ih, b_hh, 2048, Zih, nullptr, 3072);
    smallgemm_k<<<1024, 256, 0, stream>>>(z, out_w, 1152, 1024, out_b, nullptr, 0, Zout, nullptr, 1024);
    egemm_k<<<768, 256, 0, stream>>>(Emb_bf, Wihh_bf, E);

    decoder_k<<<256, 256, 0, stream>>>(Whh_bf, Wout_bf, E, Zih, Zout, b_hh, toks, hf, Hx, out,
                                       flags);
}